// Round 4
// baseline (439.014 us; speedup 1.0000x reference)
//
#include <hip/hip_runtime.h>
#include <hip/hip_bf16.h>
#include <math.h>

#define W_    384
#define H_    384
#define HW_   (384*384)
#define C_    256
#define NOBJ  16
#define NP    128
#define N2    2048
#define NF1   (NOBJ*NP)            // 2048 key points
#define NPTS  (NOBJ*NP + NOBJ*N2)  // 34816 total sampled points
#define NG    16                   // n-groups of 128 in simdist
#define NT    8                    // 16-wide n-tiles per group

typedef __attribute__((ext_vector_type(8))) short short8;
typedef __attribute__((ext_vector_type(4))) float f32x4;

__device__ __forceinline__ unsigned short f2bf(float v) {
    unsigned int u = __float_as_uint(v);
    u += 0x7fffu + ((u >> 16) & 1u);            // RNE f32->bf16
    return (unsigned short)(u >> 16);
}

// ---------------------------------------------------------------------------
// Kernel 1: fused bilinear gather-sample straight from feats [C,H,W] f32.
// Thread = (point, 64-channel quarter); 64 points per block. Per channel:
// two float2 loads (2x2 patch, rows W_*4 B apart), 4 FMA, pack to bf16.
// Zero-padding is folded into the weights (clamped patch base is exact since
// OOB taps carry zero weight). feats (151 MB) < LLC so re-reads are cached;
// bound is ~17.8M uncoalesced L1 transactions (~29 us) overlapping HBM.
// ---------------------------------------------------------------------------
__global__ __launch_bounds__(256) void k_gsample(const float* __restrict__ kpts,
                                                 const float* __restrict__ ps2,
                                                 const float* __restrict__ feats,
                                                 unsigned short* __restrict__ f12) {
    int t  = threadIdx.x;
    int pl = t & 63;                    // point within block
    int cq = t >> 6;                    // channel quarter 0..3
    int point = blockIdx.x * 64 + pl;   // NPTS = 544*64 exactly

    const float* src = (point < NF1) ? (kpts + (size_t)point * 2)
                                     : (ps2 + (size_t)(point - NF1) * 2);
    // img_size == (W,H): normalization cancels; align_corners=False => -0.5
    float x = src[0] - 0.5f, y = src[1] - 0.5f;
    float xf = floorf(x), yf = floorf(y);
    int ix0 = (int)xf, iy0 = (int)yf;
    float fx = x - xf, fy = y - yf;

    // Patch base clamped to [0, dim-2]; fold zero-pad into weights.
    int ixb = min(max(ix0, 0), W_ - 2);
    int iyb = min(max(iy0, 0), H_ - 2);
    float wA = (ix0 < 0) ? fx : ((ix0 >= W_ - 1) ? 0.f : 1.f - fx); // weight of v[ixb]
    float wB = (ix0 < 0) ? 0.f : ((ix0 >= W_ - 1) ? 1.f - fx : fx); // weight of v[ixb+1]
    float uA = (iy0 < 0) ? fy : ((iy0 >= H_ - 1) ? 0.f : 1.f - fy); // weight of row iyb
    float uB = (iy0 < 0) ? 0.f : ((iy0 >= H_ - 1) ? 1.f - fy : fy); // weight of row iyb+1
    float w00 = uA * wA, w01 = uA * wB, w10 = uB * wA, w11 = uB * wB;

    const float* p0 = feats + (size_t)(cq * 64) * HW_ + (size_t)iyb * W_ + ixb;
    unsigned short* dst = f12 + (size_t)point * C_ + cq * 64;

    for (int c8 = 0; c8 < 8; ++c8) {            // 8 groups of 8 channels
        float2 r0[8], r1[8];
        #pragma unroll
        for (int j = 0; j < 8; ++j) {
            const float* pc = p0 + (size_t)(c8 * 8 + j) * HW_;
            r0[j] = *(const float2*)(pc);
            r1[j] = *(const float2*)(pc + W_);
        }
        unsigned short u[8];
        #pragma unroll
        for (int j = 0; j < 8; ++j) {
            float v = w00 * r0[j].x + w01 * r0[j].y + w10 * r1[j].x + w11 * r1[j].y;
            u[j] = f2bf(v);
        }
        uint4 pk;
        pk.x = (unsigned)u[0] | ((unsigned)u[1] << 16);
        pk.y = (unsigned)u[2] | ((unsigned)u[3] << 16);
        pk.z = (unsigned)u[4] | ((unsigned)u[5] << 16);
        pk.w = (unsigned)u[6] | ((unsigned)u[7] << 16);
        *(uint4*)(dst + c8 * 8) = pk;
    }
}

// ---------------------------------------------------------------------------
// Kernel 2: bf16 MFMA sign-dot + masked distance stats.
// One wave per (o, 16-p tile, 128-n group). A-frags (full K=256) in 32 VGPRs;
// 8 n-tiles of 16, B-frags straight from global (L2-resident). mask =
// (dot >= 0). Partials layout: [o][p][g] for coalesced k_final reads.
// MFMA layouts per m89: C/D col=lane&15, row=(lane>>4)*4+reg;
// A/B m(n)=lane&15, k=(lane>>4)*8+j.
// ---------------------------------------------------------------------------
__global__ __launch_bounds__(256) void k_simdist(const unsigned short* __restrict__ f12,
                                                 const float* __restrict__ ps1,
                                                 const float* __restrict__ ps2,
                                                 float* __restrict__ pmin,
                                                 float* __restrict__ psum,
                                                 float* __restrict__ pcnt) {
    int wid  = blockIdx.x * 4 + (threadIdx.x >> 6);   // 0..2047
    int lane = threadIdx.x & 63;
    int ng = wid & 15;
    int pt = (wid >> 4) & 7;
    int o  = wid >> 7;
    int quad = lane >> 4, col = lane & 15;

    const short* f12s = (const short*)f12;
    const short8* aptr =
        (const short8*)(f12s + ((size_t)(o * NP + pt * 16 + col) * C_ + quad * 8));
    short8 a[8];
    #pragma unroll
    for (int kb = 0; kb < 8; ++kb) a[kb] = aptr[kb * 4];   // +32 bf16 per block

    const float2* ps1v = (const float2*)ps1;
    const float2* ps2v = (const float2*)ps2;
    float pxr[4], pyr[4];
    #pragma unroll
    for (int r = 0; r < 4; ++r) {
        float2 pc = ps1v[o * NP + pt * 16 + quad * 4 + r];
        pxr[r] = pc.x; pyr[r] = pc.y;
    }

    float mn[4] = {INFINITY, INFINITY, INFINITY, INFINITY};
    float sm[4] = {0.f, 0.f, 0.f, 0.f};
    float ct[4] = {0.f, 0.f, 0.f, 0.f};

    for (int t = 0; t < NT; ++t) {
        int nbase = ng * 128 + t * 16;
        const short8* bptr =
            (const short8*)(f12s + ((size_t)(NF1 + o * N2 + nbase + col) * C_ + quad * 8));
        f32x4 acc = {0.f, 0.f, 0.f, 0.f};
        #pragma unroll
        for (int kb = 0; kb < 8; ++kb)
            acc = __builtin_amdgcn_mfma_f32_16x16x32_bf16(a[kb], bptr[kb * 4], acc, 0, 0, 0);

        float2 nc = ps2v[o * N2 + nbase + col];   // this lane's n-column coords
        #pragma unroll
        for (int r = 0; r < 4; ++r) {
            if (acc[r] >= 0.f) {                  // sims >= 0  <=>  dot >= 0
                float dx = pxr[r] - nc.x, dy = pyr[r] - nc.y;
                float d  = sqrtf(dx * dx + dy * dy);
                mn[r] = fminf(mn[r], d); sm[r] += d; ct[r] += 1.f;
            }
        }
    }

    #pragma unroll
    for (int r = 0; r < 4; ++r) {
        #pragma unroll
        for (int off = 1; off < 16; off <<= 1) {
            mn[r] = fminf(mn[r], __shfl_xor(mn[r], off, 16));
            sm[r] += __shfl_xor(sm[r], off, 16);
            ct[r] += __shfl_xor(ct[r], off, 16);
        }
    }
    if (col == 0) {
        #pragma unroll
        for (int r = 0; r < 4; ++r) {
            int p   = pt * 16 + quad * 4 + r;
            int idx = (o * NP + p) * NG + ng;     // [o][p][g]
            pmin[idx] = mn[r]; psum[idx] = sm[r]; pcnt[idx] = ct[r];
        }
    }
}

// ---------------------------------------------------------------------------
// Kernel 3: combine group partials -> scalar loss. 1024 threads, contiguous
// 64 B reads per (o,p) pair.
// ---------------------------------------------------------------------------
__global__ __launch_bounds__(1024) void k_final(const float* __restrict__ pmin,
                                                const float* __restrict__ psum,
                                                const float* __restrict__ pcnt,
                                                float* __restrict__ out) {
    int t = threadIdx.x;
    float tot = 0.f;
    for (int pair = t; pair < NOBJ * NP; pair += 1024) {
        int base = pair * NG;
        const float4* pm = (const float4*)(pmin + base);
        const float4* ps = (const float4*)(psum + base);
        const float4* pc = (const float4*)(pcnt + base);
        float mn = INFINITY, sm = 0.f, ct = 0.f;
        #pragma unroll
        for (int g4 = 0; g4 < 4; ++g4) {
            float4 a = pm[g4], b = ps[g4], c = pc[g4];
            mn = fminf(mn, fminf(fminf(a.x, a.y), fminf(a.z, a.w)));
            sm += b.x + b.y + b.z + b.w;
            ct += c.x + c.y + c.z + c.w;
        }
        if (ct > 0.f) tot += 0.5f * (mn + sm / ct);
    }
    #pragma unroll
    for (int off = 32; off; off >>= 1) tot += __shfl_xor(tot, off, 64);
    __shared__ float wsum[16];
    if ((t & 63) == 0) wsum[t >> 6] = tot;
    __syncthreads();
    if (t < 64) {
        float v = (t < 16) ? wsum[t] : 0.f;
        #pragma unroll
        for (int off = 8; off; off >>= 1) v += __shfl_xor(v, off, 16);
        if (t == 0) out[0] = v * (1.0f / (NOBJ * NP));
    }
}

// ---------------------------------------------------------------------------
extern "C" void kernel_launch(void* const* d_in, const int* in_sizes, int n_in,
                              void* d_out, int out_size, void* d_ws, size_t ws_size,
                              hipStream_t stream) {
    const float* ps1   = (const float*)d_in[0];  // [16,128,2]
    const float* ps2   = (const float*)d_in[1];  // [16,2048,2]
    const float* feats = (const float*)d_in[2];  // [1,256,384,384]
    const float* kpts  = (const float*)d_in[3];  // [2048,2]
    float* out = (float*)d_out;

    const size_t sz_f12  = (size_t)NPTS * C_ * sizeof(unsigned short);  // 17,825,792
    const size_t sz_part = (size_t)NOBJ * NP * NG * sizeof(float);      //    131,072

    char* ws = (char*)d_ws;
    unsigned short* f12 = (unsigned short*)ws;
    float* pmin = (float*)(ws + sz_f12);
    float* psum = (float*)(ws + sz_f12 + sz_part);
    float* pcnt = (float*)(ws + sz_f12 + 2 * sz_part);

    k_gsample<<<NPTS / 64, 256, 0, stream>>>(kpts, ps2, feats, f12);
    k_simdist<<<NOBJ * 8 * NG / 4, 256, 0, stream>>>(f12, ps1, ps2, pmin, psum, pcnt);
    k_final<<<1, 1024, 0, stream>>>(pmin, psum, pcnt, out);
}

// Round 5
// 366.363 us; speedup vs baseline: 1.1983x; 1.1983x over previous
//
#include <hip/hip_runtime.h>
#include <hip/hip_bf16.h>
#include <math.h>

#define W_    384
#define H_    384
#define HW_   (384*384)
#define C_    256
#define NOBJ  16
#define NP    128
#define N2    2048
#define NF1   (NOBJ*NP)            // 2048 key points
#define NPTS  (NOBJ*NP + NOBJ*N2)  // 34816 total sampled points
#define NG    16                   // n-groups of 128 in simdist
#define NT    8                    // 16-wide n-tiles per group

#define TX    64                   // spatial tile width  (x)
#define TY    8                    // spatial tile height (y)
#define NTX   (W_/TX)              // 6
#define NTY   (H_/TY)              // 48
#define NTILE (NTX*NTY)            // 288
#define CAP   320                  // max points per tile (mean 121, ~20 sigma)

typedef __attribute__((ext_vector_type(8))) short short8;
typedef __attribute__((ext_vector_type(4))) float f32x4;

__device__ __forceinline__ unsigned short f2bf(float v) {
    unsigned int u = __float_as_uint(v);
    u += 0x7fffu + ((u >> 16) & 1u);            // RNE f32->bf16
    return (unsigned short)(u >> 16);
}

// Clamped patch base + zero-pad-folded bilinear weights (exact; OOB taps have
// zero weight). Must be bit-identical between k_bin and k_gather.
__device__ __forceinline__ void patch_setup(float px, float py,
                                            int& ixb, int& iyb,
                                            float& w00, float& w01,
                                            float& w10, float& w11) {
    float x = px - 0.5f, y = py - 0.5f;        // img_size==(W,H): norm cancels
    float xf = floorf(x), yf = floorf(y);
    int ix0 = (int)xf, iy0 = (int)yf;
    float fx = x - xf, fy = y - yf;
    ixb = min(max(ix0, 0), W_ - 2);
    iyb = min(max(iy0, 0), H_ - 2);
    float wA = (ix0 < 0) ? fx : ((ix0 >= W_ - 1) ? 0.f : 1.f - fx);
    float wB = (ix0 < 0) ? 0.f : ((ix0 >= W_ - 1) ? 1.f - fx : fx);
    float uA = (iy0 < 0) ? fy : ((iy0 >= H_ - 1) ? 0.f : 1.f - fy);
    float uB = (iy0 < 0) ? 0.f : ((iy0 >= H_ - 1) ? 1.f - fy : fy);
    w00 = uA * wA; w01 = uA * wB; w10 = uB * wA; w11 = uB * wB;
}

// ---------------------------------------------------------------------------
// Kernel 0: bin points by spatial tile of their (clamped) patch base.
// ---------------------------------------------------------------------------
__global__ __launch_bounds__(256) void k_bin(const float* __restrict__ kpts,
                                             const float* __restrict__ ps2,
                                             int* __restrict__ counts,
                                             int* __restrict__ list) {
    int p = blockIdx.x * 256 + threadIdx.x;    // NPTS = 136*256 exactly
    const float* src = (p < NF1) ? (kpts + (size_t)p * 2)
                                 : (ps2 + (size_t)(p - NF1) * 2);
    int ixb, iyb; float w00, w01, w10, w11;
    patch_setup(src[0], src[1], ixb, iyb, w00, w01, w10, w11);
    int tile = (iyb >> 3) * NTX + (ixb >> 6);
    int slot = atomicAdd(&counts[tile], 1);
    if (slot < CAP) list[tile * CAP + slot] = p;
}

// ---------------------------------------------------------------------------
// Kernel 1: fused tile-staged bilinear sampler.
// Block = (spatial tile, 64-channel chunk). Phase 1: coalesced load of the
// 65x9x64ch f32 halo tile -> LDS bf16 (74.9 KB, 2 blocks/CU). Phase 2: each
// binned point sampled by 8 lanes (8 ch each): 4 x 16 B LDS taps, weights
// per patch_setup, 128 B coalesced bf16 write to f12.
// LDS layout: [g(8)][dy(9)][dx(65)][c7(8)] bf16 — 8-lane groups stride 4
// banks, conflict-free within a point.
// ---------------------------------------------------------------------------
__global__ __launch_bounds__(256) void k_gather(const float* __restrict__ kpts,
                                                const float* __restrict__ ps2,
                                                const float* __restrict__ feats,
                                                const int* __restrict__ counts,
                                                const int* __restrict__ list,
                                                unsigned short* __restrict__ f12) {
    __shared__ unsigned short lds[8 * 9 * 65 * 8];   // 37440 bf16 = 74880 B
    int b    = blockIdx.x;
    int tile = b >> 2;
    int cq   = b & 3;
    int ty = tile / NTX, tx = tile - ty * NTX;
    int x0 = tx * TX, y0 = ty * TY;
    int t  = threadIdx.x;

    for (int f = t; f < 64 * 585; f += 256) {
        int c  = f / 585;
        int r  = f - c * 585;
        int dy = r / 65;
        int dx = r - dy * 65;
        int yy = min(y0 + dy, H_ - 1);     // clamped halo rows are never read
        int xx = min(x0 + dx, W_ - 1);
        float v = feats[(size_t)(cq * 64 + c) * HW_ + yy * W_ + xx];
        lds[(((c >> 3) * 9 + dy) * 65 + dx) * 8 + (c & 7)] = f2bf(v);
    }
    __syncthreads();

    int cnt  = counts[tile];
    int lane = t & 63, wave = t >> 6;
    int sub  = lane >> 3;                  // 8 points in flight per wave
    int g    = lane & 7;                   // channel octet within chunk

    for (int i = wave * 8 + sub; i < cnt; i += 32) {
        int point = list[tile * CAP + i];
        const float* src = (point < NF1) ? (kpts + (size_t)point * 2)
                                         : (ps2 + (size_t)(point - NF1) * 2);
        int ixb, iyb; float w00, w01, w10, w11;
        patch_setup(src[0], src[1], ixb, iyb, w00, w01, w10, w11);
        int dxb = ixb - x0, dyb = iyb - y0;

        const uint4* r0 = (const uint4*)&lds[((g * 9 + dyb) * 65 + dxb) * 8];
        const uint4* r1 = (const uint4*)&lds[((g * 9 + dyb + 1) * 65 + dxb) * 8];
        uint4 t00 = r0[0], t01 = r0[1];
        uint4 t10 = r1[0], t11 = r1[1];

        unsigned short u[8];
        const unsigned* a00 = (const unsigned*)&t00;
        const unsigned* a01 = (const unsigned*)&t01;
        const unsigned* a10 = (const unsigned*)&t10;
        const unsigned* a11 = (const unsigned*)&t11;
        #pragma unroll
        for (int j = 0; j < 4; ++j) {
            float vlo = w00 * __uint_as_float(a00[j] << 16)
                      + w01 * __uint_as_float(a01[j] << 16)
                      + w10 * __uint_as_float(a10[j] << 16)
                      + w11 * __uint_as_float(a11[j] << 16);
            float vhi = w00 * __uint_as_float(a00[j] & 0xffff0000u)
                      + w01 * __uint_as_float(a01[j] & 0xffff0000u)
                      + w10 * __uint_as_float(a10[j] & 0xffff0000u)
                      + w11 * __uint_as_float(a11[j] & 0xffff0000u);
            u[j * 2]     = f2bf(vlo);
            u[j * 2 + 1] = f2bf(vhi);
        }
        uint4 pk;
        pk.x = (unsigned)u[0] | ((unsigned)u[1] << 16);
        pk.y = (unsigned)u[2] | ((unsigned)u[3] << 16);
        pk.z = (unsigned)u[4] | ((unsigned)u[5] << 16);
        pk.w = (unsigned)u[6] | ((unsigned)u[7] << 16);
        *(uint4*)(f12 + (size_t)point * C_ + cq * 64 + g * 8) = pk;
    }
}

// ---------------------------------------------------------------------------
// Kernel 2: bf16 MFMA sign-dot + masked distance stats (unchanged from R3).
// ---------------------------------------------------------------------------
__global__ __launch_bounds__(256) void k_simdist(const unsigned short* __restrict__ f12,
                                                 const float* __restrict__ ps1,
                                                 const float* __restrict__ ps2,
                                                 float* __restrict__ pmin,
                                                 float* __restrict__ psum,
                                                 float* __restrict__ pcnt) {
    int wid  = blockIdx.x * 4 + (threadIdx.x >> 6);   // 0..2047
    int lane = threadIdx.x & 63;
    int ng = wid & 15;
    int pt = (wid >> 4) & 7;
    int o  = wid >> 7;
    int quad = lane >> 4, col = lane & 15;

    const short* f12s = (const short*)f12;
    const short8* aptr =
        (const short8*)(f12s + ((size_t)(o * NP + pt * 16 + col) * C_ + quad * 8));
    short8 a[8];
    #pragma unroll
    for (int kb = 0; kb < 8; ++kb) a[kb] = aptr[kb * 4];

    const float2* ps1v = (const float2*)ps1;
    const float2* ps2v = (const float2*)ps2;
    float pxr[4], pyr[4];
    #pragma unroll
    for (int r = 0; r < 4; ++r) {
        float2 pc = ps1v[o * NP + pt * 16 + quad * 4 + r];
        pxr[r] = pc.x; pyr[r] = pc.y;
    }

    float mn[4] = {INFINITY, INFINITY, INFINITY, INFINITY};
    float sm[4] = {0.f, 0.f, 0.f, 0.f};
    float ct[4] = {0.f, 0.f, 0.f, 0.f};

    for (int t = 0; t < NT; ++t) {
        int nbase = ng * 128 + t * 16;
        const short8* bptr =
            (const short8*)(f12s + ((size_t)(NF1 + o * N2 + nbase + col) * C_ + quad * 8));
        f32x4 acc = {0.f, 0.f, 0.f, 0.f};
        #pragma unroll
        for (int kb = 0; kb < 8; ++kb)
            acc = __builtin_amdgcn_mfma_f32_16x16x32_bf16(a[kb], bptr[kb * 4], acc, 0, 0, 0);

        float2 nc = ps2v[o * N2 + nbase + col];
        #pragma unroll
        for (int r = 0; r < 4; ++r) {
            if (acc[r] >= 0.f) {                  // sims >= 0  <=>  dot >= 0
                float dx = pxr[r] - nc.x, dy = pyr[r] - nc.y;
                float d  = sqrtf(dx * dx + dy * dy);
                mn[r] = fminf(mn[r], d); sm[r] += d; ct[r] += 1.f;
            }
        }
    }

    #pragma unroll
    for (int r = 0; r < 4; ++r) {
        #pragma unroll
        for (int off = 1; off < 16; off <<= 1) {
            mn[r] = fminf(mn[r], __shfl_xor(mn[r], off, 16));
            sm[r] += __shfl_xor(sm[r], off, 16);
            ct[r] += __shfl_xor(ct[r], off, 16);
        }
    }
    if (col == 0) {
        #pragma unroll
        for (int r = 0; r < 4; ++r) {
            int p   = pt * 16 + quad * 4 + r;
            int idx = (o * NP + p) * NG + ng;     // [o][p][g]
            pmin[idx] = mn[r]; psum[idx] = sm[r]; pcnt[idx] = ct[r];
        }
    }
}

// ---------------------------------------------------------------------------
// Kernel 3: combine group partials -> scalar loss.
// ---------------------------------------------------------------------------
__global__ __launch_bounds__(1024) void k_final(const float* __restrict__ pmin,
                                                const float* __restrict__ psum,
                                                const float* __restrict__ pcnt,
                                                float* __restrict__ out) {
    int t = threadIdx.x;
    float tot = 0.f;
    for (int pair = t; pair < NOBJ * NP; pair += 1024) {
        int base = pair * NG;
        const float4* pm = (const float4*)(pmin + base);
        const float4* ps = (const float4*)(psum + base);
        const float4* pc = (const float4*)(pcnt + base);
        float mn = INFINITY, sm = 0.f, ct = 0.f;
        #pragma unroll
        for (int g4 = 0; g4 < 4; ++g4) {
            float4 a = pm[g4], bq = ps[g4], c = pc[g4];
            mn = fminf(mn, fminf(fminf(a.x, a.y), fminf(a.z, a.w)));
            sm += bq.x + bq.y + bq.z + bq.w;
            ct += c.x + c.y + c.z + c.w;
        }
        if (ct > 0.f) tot += 0.5f * (mn + sm / ct);
    }
    #pragma unroll
    for (int off = 32; off; off >>= 1) tot += __shfl_xor(tot, off, 64);
    __shared__ float wsum[16];
    if ((t & 63) == 0) wsum[t >> 6] = tot;
    __syncthreads();
    if (t < 64) {
        float v = (t < 16) ? wsum[t] : 0.f;
        #pragma unroll
        for (int off = 8; off; off >>= 1) v += __shfl_xor(v, off, 16);
        if (t == 0) out[0] = v * (1.0f / (NOBJ * NP));
    }
}

// ---------------------------------------------------------------------------
extern "C" void kernel_launch(void* const* d_in, const int* in_sizes, int n_in,
                              void* d_out, int out_size, void* d_ws, size_t ws_size,
                              hipStream_t stream) {
    const float* ps1   = (const float*)d_in[0];  // [16,128,2]
    const float* ps2   = (const float*)d_in[1];  // [16,2048,2]
    const float* feats = (const float*)d_in[2];  // [1,256,384,384]
    const float* kpts  = (const float*)d_in[3];  // [2048,2]
    float* out = (float*)d_out;

    const size_t sz_f12  = (size_t)NPTS * C_ * sizeof(unsigned short);  // 17,825,792
    const size_t sz_part = (size_t)NOBJ * NP * NG * sizeof(float);      //    131,072
    const size_t sz_cnt  = (size_t)NTILE * sizeof(int);                 //      1,152
    const size_t sz_cnt_pad = 4096;                                     // alignment
    const size_t sz_list = (size_t)NTILE * CAP * sizeof(int);           //    368,640

    char* ws = (char*)d_ws;
    unsigned short* f12 = (unsigned short*)ws;
    float* pmin  = (float*)(ws + sz_f12);
    float* psum  = (float*)(ws + sz_f12 + sz_part);
    float* pcnt  = (float*)(ws + sz_f12 + 2 * sz_part);
    int*   cnts  = (int*)  (ws + sz_f12 + 3 * sz_part);
    int*   list  = (int*)  (ws + sz_f12 + 3 * sz_part + sz_cnt_pad);
    (void)sz_cnt; (void)sz_list;

    hipMemsetAsync(cnts, 0, sz_cnt, stream);    // ws is poisoned 0xAA each call
    k_bin<<<NPTS / 256, 256, 0, stream>>>(kpts, ps2, cnts, list);
    k_gather<<<NTILE * 4, 256, 0, stream>>>(kpts, ps2, feats, cnts, list, f12);
    k_simdist<<<NOBJ * 8 * NG / 4, 256, 0, stream>>>(f12, ps1, ps2, pmin, psum, pcnt);
    k_final<<<1, 1024, 0, stream>>>(pmin, psum, pcnt, out);
}

// Round 6
// 290.661 us; speedup vs baseline: 1.5104x; 1.2604x over previous
//
#include <hip/hip_runtime.h>
#include <hip/hip_bf16.h>
#include <math.h>

#define W_    384
#define H_    384
#define HW_   (384*384)
#define C_    256
#define NOBJ  16
#define NP    128
#define N2    2048
#define NF1   (NOBJ*NP)            // 2048 key points
#define NPTS  (NOBJ*NP + NOBJ*N2)  // 34816 total sampled points
#define NG    16                   // n-groups of 128 in simdist
#define NT    8                    // 16-wide n-tiles per group

#define TX    63                   // spatial tile width  (halo = 64 cols, pow2)
#define TY    8                    // spatial tile height (halo = 9 rows)
#define NTX   7                    // ceil(384/63); last tile 6 px wide
#define NTY   48
#define NTILE (NTX*NTY)            // 336
#define CAP   256                  // max pts/tile (mean ~119, sigma ~11)
#define CCH   32                   // channels per gather block
#define DXP   68                   // padded dx stride (shorts): 136 B, 8B-aligned
#define CST   (9*DXP)              // c stride in shorts = 612

typedef __attribute__((ext_vector_type(8))) short short8;
typedef __attribute__((ext_vector_type(4))) float f32x4;

__device__ __forceinline__ unsigned short f2bf(float v) {
    unsigned int u = __float_as_uint(v);
    u += 0x7fffu + ((u >> 16) & 1u);            // RNE f32->bf16
    return (unsigned short)(u >> 16);
}
__device__ __forceinline__ float bf2f(unsigned short s) {
    return __uint_as_float((unsigned)s << 16);
}

// Clamped patch base + zero-pad-folded bilinear weights (exact: OOB taps have
// zero weight). Must be identical between k_bin and k_gather.
__device__ __forceinline__ void patch_setup(float px, float py,
                                            int& ixb, int& iyb,
                                            float& w00, float& w01,
                                            float& w10, float& w11) {
    float x = px - 0.5f, y = py - 0.5f;        // img_size==(W,H): norm cancels
    float xf = floorf(x), yf = floorf(y);
    int ix0 = (int)xf, iy0 = (int)yf;
    float fx = x - xf, fy = y - yf;
    ixb = min(max(ix0, 0), W_ - 2);
    iyb = min(max(iy0, 0), H_ - 2);
    float wA = (ix0 < 0) ? fx : ((ix0 >= W_ - 1) ? 0.f : 1.f - fx);
    float wB = (ix0 < 0) ? 0.f : ((ix0 >= W_ - 1) ? 1.f - fx : fx);
    float uA = (iy0 < 0) ? fy : ((iy0 >= H_ - 1) ? 0.f : 1.f - fy);
    float uB = (iy0 < 0) ? 0.f : ((iy0 >= H_ - 1) ? 1.f - fy : fy);
    w00 = uA * wA; w01 = uA * wB; w10 = uB * wA; w11 = uB * wB;
}

// ---------------------------------------------------------------------------
// Kernel 0: bin points by spatial tile of the clamped patch base; stage
// (x, y, idx) as float4 so the gather reads one coalesced 16 B per point.
// ---------------------------------------------------------------------------
__global__ __launch_bounds__(256) void k_bin(const float* __restrict__ kpts,
                                             const float* __restrict__ ps2,
                                             int* __restrict__ counts,
                                             float4* __restrict__ list) {
    int p = blockIdx.x * 256 + threadIdx.x;    // NPTS = 136*256 exactly
    const float* src = (p < NF1) ? (kpts + (size_t)p * 2)
                                 : (ps2 + (size_t)(p - NF1) * 2);
    float px = src[0], py = src[1];
    int ixb, iyb; float w00, w01, w10, w11;
    patch_setup(px, py, ixb, iyb, w00, w01, w10, w11);
    int tile = (iyb >> 3) * NTX + ixb / TX;    // compiler emits magic-mul
    int slot = atomicAdd(&counts[tile], 1);
    if (slot < CAP) {
        float4 e; e.x = px; e.y = py; e.z = __int_as_float(p); e.w = 0.f;
        list[tile * CAP + slot] = e;
    }
}

// ---------------------------------------------------------------------------
// Kernel 1: fused tile-staged bilinear sampler.
// Block = (tile, 32-ch chunk). Phase 1: float4 global loads (1 KB/wave-instr)
// -> LDS bf16 [c][dy][dx pad 68], ushort4 writes, conflict-free (dx-lanes
// word-stride 2 cover all banks once; c-lanes rotate +18). 39.2 KB -> 4
// blocks/CU. Phase 2: 16 points in flight/wave, 4 lanes/point (8 ch each),
// u16 LDS taps, 64 B coalesced f12 write per point.
// ---------------------------------------------------------------------------
__global__ __launch_bounds__(256) void k_gather(const float* __restrict__ feats,
                                                const int* __restrict__ counts,
                                                const float4* __restrict__ list,
                                                unsigned short* __restrict__ f12) {
    __shared__ unsigned short lds[CCH * CST];   // 32*612 shorts = 39168 B
    int b    = blockIdx.x;
    int tile = b >> 3;
    int cq   = b & 7;
    int ty = tile / NTX, tx = tile - ty * NTX;  // once per block
    int x0 = tx * TX, y0 = ty * TY;
    int t  = threadIdx.x;
    int cb = cq * CCH;
    bool edge = (tx == NTX - 1);                // cols x0+6..63 are clamped dups

    #pragma unroll
    for (int half = 0; half < 2; ++half) {
        int id  = half * 256 + t;               // 0..511
        int c   = id >> 4;                      // 0..31
        int dx4 = (id & 15) * 4;
        const float* cbase = feats + (size_t)(cb + c) * HW_;
        unsigned short* ldst = &lds[c * CST + dx4];
        #pragma unroll
        for (int dy = 0; dy < 9; ++dy) {
            int yy = min(y0 + dy, H_ - 1);
            float4 v;
            if (!edge) {
                v = *(const float4*)(cbase + yy * W_ + x0 + dx4);
            } else {
                const float* rowp = cbase + yy * W_;
                v.x = rowp[min(x0 + dx4 + 0, W_ - 1)];
                v.y = rowp[min(x0 + dx4 + 1, W_ - 1)];
                v.z = rowp[min(x0 + dx4 + 2, W_ - 1)];
                v.w = rowp[min(x0 + dx4 + 3, W_ - 1)];
            }
            ushort4 pk;
            pk.x = f2bf(v.x); pk.y = f2bf(v.y); pk.z = f2bf(v.z); pk.w = f2bf(v.w);
            *(ushort4*)(ldst + dy * DXP) = pk;
        }
    }
    __syncthreads();

    int cnt  = min(counts[tile], CAP);
    int lane = t & 63, wave = t >> 6;
    int sub  = lane >> 2;                       // 16 points in flight per wave
    int g    = lane & 3;                        // channel octet within chunk

    for (int i = wave * 16 + sub; i < cnt; i += 64) {
        float4 e = list[tile * CAP + i];
        int point = __float_as_int(e.z);
        int ixb, iyb; float w00, w01, w10, w11;
        patch_setup(e.x, e.y, ixb, iyb, w00, w01, w10, w11);
        int dxb = ixb - x0, dyb = iyb - y0;

        unsigned short u[8];
        #pragma unroll
        for (int j = 0; j < 8; ++j) {
            const unsigned short* base = &lds[(g * 8 + j) * CST + dyb * DXP + dxb];
            float v = w00 * bf2f(base[0])   + w01 * bf2f(base[1])
                    + w10 * bf2f(base[DXP]) + w11 * bf2f(base[DXP + 1]);
            u[j] = f2bf(v);
        }
        uint4 pk;
        pk.x = (unsigned)u[0] | ((unsigned)u[1] << 16);
        pk.y = (unsigned)u[2] | ((unsigned)u[3] << 16);
        pk.z = (unsigned)u[4] | ((unsigned)u[5] << 16);
        pk.w = (unsigned)u[6] | ((unsigned)u[7] << 16);
        *(uint4*)(f12 + (size_t)point * C_ + cb + g * 8) = pk;
    }
}

// ---------------------------------------------------------------------------
// Kernel 2: bf16 MFMA sign-dot + masked distance stats (unchanged from R3).
// ---------------------------------------------------------------------------
__global__ __launch_bounds__(256) void k_simdist(const unsigned short* __restrict__ f12,
                                                 const float* __restrict__ ps1,
                                                 const float* __restrict__ ps2,
                                                 float* __restrict__ pmin,
                                                 float* __restrict__ psum,
                                                 float* __restrict__ pcnt) {
    int wid  = blockIdx.x * 4 + (threadIdx.x >> 6);   // 0..2047
    int lane = threadIdx.x & 63;
    int ng = wid & 15;
    int pt = (wid >> 4) & 7;
    int o  = wid >> 7;
    int quad = lane >> 4, col = lane & 15;

    const short* f12s = (const short*)f12;
    const short8* aptr =
        (const short8*)(f12s + ((size_t)(o * NP + pt * 16 + col) * C_ + quad * 8));
    short8 a[8];
    #pragma unroll
    for (int kb = 0; kb < 8; ++kb) a[kb] = aptr[kb * 4];

    const float2* ps1v = (const float2*)ps1;
    const float2* ps2v = (const float2*)ps2;
    float pxr[4], pyr[4];
    #pragma unroll
    for (int r = 0; r < 4; ++r) {
        float2 pc = ps1v[o * NP + pt * 16 + quad * 4 + r];
        pxr[r] = pc.x; pyr[r] = pc.y;
    }

    float mn[4] = {INFINITY, INFINITY, INFINITY, INFINITY};
    float sm[4] = {0.f, 0.f, 0.f, 0.f};
    float ct[4] = {0.f, 0.f, 0.f, 0.f};

    for (int t = 0; t < NT; ++t) {
        int nbase = ng * 128 + t * 16;
        const short8* bptr =
            (const short8*)(f12s + ((size_t)(NF1 + o * N2 + nbase + col) * C_ + quad * 8));
        f32x4 acc = {0.f, 0.f, 0.f, 0.f};
        #pragma unroll
        for (int kb = 0; kb < 8; ++kb)
            acc = __builtin_amdgcn_mfma_f32_16x16x32_bf16(a[kb], bptr[kb * 4], acc, 0, 0, 0);

        float2 nc = ps2v[o * N2 + nbase + col];
        #pragma unroll
        for (int r = 0; r < 4; ++r) {
            if (acc[r] >= 0.f) {                  // sims >= 0  <=>  dot >= 0
                float dx = pxr[r] - nc.x, dy = pyr[r] - nc.y;
                float d  = sqrtf(dx * dx + dy * dy);
                mn[r] = fminf(mn[r], d); sm[r] += d; ct[r] += 1.f;
            }
        }
    }

    #pragma unroll
    for (int r = 0; r < 4; ++r) {
        #pragma unroll
        for (int off = 1; off < 16; off <<= 1) {
            mn[r] = fminf(mn[r], __shfl_xor(mn[r], off, 16));
            sm[r] += __shfl_xor(sm[r], off, 16);
            ct[r] += __shfl_xor(ct[r], off, 16);
        }
    }
    if (col == 0) {
        #pragma unroll
        for (int r = 0; r < 4; ++r) {
            int p   = pt * 16 + quad * 4 + r;
            int idx = (o * NP + p) * NG + ng;     // [o][p][g]
            pmin[idx] = mn[r]; psum[idx] = sm[r]; pcnt[idx] = ct[r];
        }
    }
}

// ---------------------------------------------------------------------------
// Kernel 3: combine group partials -> scalar loss.
// ---------------------------------------------------------------------------
__global__ __launch_bounds__(1024) void k_final(const float* __restrict__ pmin,
                                                const float* __restrict__ psum,
                                                const float* __restrict__ pcnt,
                                                float* __restrict__ out) {
    int t = threadIdx.x;
    float tot = 0.f;
    for (int pair = t; pair < NOBJ * NP; pair += 1024) {
        int base = pair * NG;
        const float4* pm = (const float4*)(pmin + base);
        const float4* ps = (const float4*)(psum + base);
        const float4* pc = (const float4*)(pcnt + base);
        float mn = INFINITY, sm = 0.f, ct = 0.f;
        #pragma unroll
        for (int g4 = 0; g4 < 4; ++g4) {
            float4 a = pm[g4], bq = ps[g4], c = pc[g4];
            mn = fminf(mn, fminf(fminf(a.x, a.y), fminf(a.z, a.w)));
            sm += bq.x + bq.y + bq.z + bq.w;
            ct += c.x + c.y + c.z + c.w;
        }
        if (ct > 0.f) tot += 0.5f * (mn + sm / ct);
    }
    #pragma unroll
    for (int off = 32; off; off >>= 1) tot += __shfl_xor(tot, off, 64);
    __shared__ float wsum[16];
    if ((t & 63) == 0) wsum[t >> 6] = tot;
    __syncthreads();
    if (t < 64) {
        float v = (t < 16) ? wsum[t] : 0.f;
        #pragma unroll
        for (int off = 8; off; off >>= 1) v += __shfl_xor(v, off, 16);
        if (t == 0) out[0] = v * (1.0f / (NOBJ * NP));
    }
}

// ---------------------------------------------------------------------------
extern "C" void kernel_launch(void* const* d_in, const int* in_sizes, int n_in,
                              void* d_out, int out_size, void* d_ws, size_t ws_size,
                              hipStream_t stream) {
    const float* ps1   = (const float*)d_in[0];  // [16,128,2]
    const float* ps2   = (const float*)d_in[1];  // [16,2048,2]
    const float* feats = (const float*)d_in[2];  // [1,256,384,384]
    const float* kpts  = (const float*)d_in[3];  // [2048,2]
    float* out = (float*)d_out;

    const size_t sz_f12  = (size_t)NPTS * C_ * sizeof(unsigned short);  // 17,825,792
    const size_t sz_part = (size_t)NOBJ * NP * NG * sizeof(float);      //    131,072
    const size_t sz_cnt  = (size_t)NTILE * sizeof(int);                 //      1,344
    const size_t sz_cnt_pad = 4096;
    // list: NTILE*CAP*16 B = 1,376,256

    char* ws = (char*)d_ws;
    unsigned short* f12 = (unsigned short*)ws;
    float*  pmin = (float*) (ws + sz_f12);
    float*  psum = (float*) (ws + sz_f12 + sz_part);
    float*  pcnt = (float*) (ws + sz_f12 + 2 * sz_part);
    int*    cnts = (int*)   (ws + sz_f12 + 3 * sz_part);
    float4* list = (float4*)(ws + sz_f12 + 3 * sz_part + sz_cnt_pad);

    hipMemsetAsync(cnts, 0, sz_cnt, stream);    // ws is poisoned 0xAA each call
    k_bin<<<NPTS / 256, 256, 0, stream>>>(kpts, ps2, cnts, list);
    k_gather<<<NTILE * 8, 256, 0, stream>>>(feats, cnts, list, f12);
    k_simdist<<<NOBJ * 8 * NG / 4, 256, 0, stream>>>(f12, ps1, ps2, pmin, psum, pcnt);
    k_final<<<1, 1024, 0, stream>>>(pmin, psum, pcnt, out);
}

// Round 7
// 276.508 us; speedup vs baseline: 1.5877x; 1.0512x over previous
//
#include <hip/hip_runtime.h>
#include <hip/hip_bf16.h>
#include <math.h>

#define W_    384
#define H_    384
#define HW_   (384*384)
#define C_    256
#define NOBJ  16
#define NP    128
#define N2    2048
#define NF1   (NOBJ*NP)            // 2048 key points
#define NPTS  (NOBJ*NP + NOBJ*N2)  // 34816 total sampled points
#define NG    16                   // n-groups of 128 in simdist
#define NT    8                    // 16-wide n-tiles per group

#define TX    63                   // spatial tile width  (halo = 64 cols)
#define TY    8                    // spatial tile height (halo = 9 rows)
#define NTX   7                    // ceil(384/63); last tile 6 px wide
#define NTY   48
#define NTILE (NTX*NTY)            // 336
#define CAP   256                  // max pts/tile (mean ~104)
#define CCH   16                   // channels per gather block (16 blocks/tile)

typedef __attribute__((ext_vector_type(8))) short short8;
typedef __attribute__((ext_vector_type(4))) float f32x4;

__device__ __forceinline__ unsigned short f2bf(float v) {
    unsigned int u = __float_as_uint(v);
    u += 0x7fffu + ((u >> 16) & 1u);            // RNE f32->bf16
    return (unsigned short)(u >> 16);
}

// Clamped patch base + zero-pad-folded bilinear weights (exact: OOB taps have
// zero weight). Must be identical between k_bin and k_gather.
__device__ __forceinline__ void patch_setup(float px, float py,
                                            int& ixb, int& iyb,
                                            float& w00, float& w01,
                                            float& w10, float& w11) {
    float x = px - 0.5f, y = py - 0.5f;        // img_size==(W,H): norm cancels
    float xf = floorf(x), yf = floorf(y);
    int ix0 = (int)xf, iy0 = (int)yf;
    float fx = x - xf, fy = y - yf;
    ixb = min(max(ix0, 0), W_ - 2);
    iyb = min(max(iy0, 0), H_ - 2);
    float wA = (ix0 < 0) ? fx : ((ix0 >= W_ - 1) ? 0.f : 1.f - fx);
    float wB = (ix0 < 0) ? 0.f : ((ix0 >= W_ - 1) ? 1.f - fx : fx);
    float uA = (iy0 < 0) ? fy : ((iy0 >= H_ - 1) ? 0.f : 1.f - fy);
    float uB = (iy0 < 0) ? 0.f : ((iy0 >= H_ - 1) ? 1.f - fy : fy);
    w00 = uA * wA; w01 = uA * wB; w10 = uB * wA; w11 = uB * wB;
}

// ---------------------------------------------------------------------------
// Kernel 0: bin points by spatial tile of the clamped patch base; stage
// (x, y, idx) as float4 so the gather reads one coalesced 16 B per point.
// ---------------------------------------------------------------------------
__global__ __launch_bounds__(256) void k_bin(const float* __restrict__ kpts,
                                             const float* __restrict__ ps2,
                                             int* __restrict__ counts,
                                             float4* __restrict__ list) {
    int p = blockIdx.x * 256 + threadIdx.x;    // NPTS = 136*256 exactly
    const float* src = (p < NF1) ? (kpts + (size_t)p * 2)
                                 : (ps2 + (size_t)(p - NF1) * 2);
    float px = src[0], py = src[1];
    int ixb, iyb; float w00, w01, w10, w11;
    patch_setup(px, py, ixb, iyb, w00, w01, w10, w11);
    int tile = (iyb >> 3) * NTX + ixb / TX;    // magic-mul division
    int slot = atomicAdd(&counts[tile], 1);
    if (slot < CAP) {
        float4 e; e.x = px; e.y = py; e.z = __int_as_float(p); e.w = 0.f;
        list[tile * CAP + slot] = e;
    }
}

// ---------------------------------------------------------------------------
// Kernel 1: fused tile-staged bilinear sampler, latency-fixed.
// Block = (tile, 16-ch chunk). Phase 1: per thread, 9 INDEPENDENT float4
// global loads into a register array (two separate unrolled loops so the
// compiler issues all loads before any LDS write), then 9 ds_write_b128 into
// the f32 tile [dy(9)][c(16)][dx(64)] (36 KB -> 4 blocks/CU). No converts.
// Phase 2: 16 points/wave in flight, 4 lanes/point x 4 ch: 16 ds_read_b32
// taps, f32 weights, bf16 pack, 8 B coalesced write per lane.
// ---------------------------------------------------------------------------
__global__ __launch_bounds__(256, 4) void k_gather(const float* __restrict__ feats,
                                                   const int* __restrict__ counts,
                                                   const float4* __restrict__ list,
                                                   unsigned short* __restrict__ f12) {
    __shared__ float lds[9 * 16 * 64];          // 36864 B
    int b    = blockIdx.x;
    int tile = b >> 4;
    int cq   = b & 15;
    int cb   = cq * CCH;
    int ty = tile / NTX, tx = tile - ty * NTX;
    int x0 = tx * TX, y0 = ty * TY;
    int t  = threadIdx.x;

    // ---- phase 1: stage 64x9 halo x 16 ch as f32 ----
    {
        int c   = t >> 4;                       // 0..15
        int dx4 = (t & 15) * 4;                 // 0,4,..,60
        size_t cgbase = (size_t)(cb + c) * HW_ + x0 + dx4;
        const size_t LIM = (size_t)HW_ * C_ - 4;   // clamp: edge tiles overrun rows
        float4 r[9];
        #pragma unroll
        for (int dy = 0; dy < 9; ++dy) {        // 9 independent loads, no LDS dep
            int yy = min(y0 + dy, H_ - 1);
            size_t gidx = cgbase + (size_t)yy * W_;
            gidx = gidx > LIM ? LIM : gidx;
            r[dy] = *(const float4*)(feats + gidx);
        }
        float* ldst = &lds[c * 64 + dx4];
        #pragma unroll
        for (int dy = 0; dy < 9; ++dy)
            *(float4*)(ldst + dy * 1024) = r[dy];
    }
    __syncthreads();

    // ---- phase 2: sample binned points from the LDS tile ----
    int cnt  = min(counts[tile], CAP);
    int lane = t & 63, wave = t >> 6;
    int sub  = lane >> 2;                       // 16 points in flight per wave
    int g    = lane & 3;                        // channel quartet within chunk

    for (int i = wave * 16 + sub; i < cnt; i += 64) {
        float4 e = list[tile * CAP + i];
        int point = __float_as_int(e.z);
        int ixb, iyb; float w00, w01, w10, w11;
        patch_setup(e.x, e.y, ixb, iyb, w00, w01, w10, w11);
        int dxb = ixb - x0, dyb = iyb - y0;
        int base0 = dyb * 1024 + (g * 4) * 64 + dxb;

        unsigned short u[4];
        #pragma unroll
        for (int j = 0; j < 4; ++j) {
            int bj = base0 + j * 64;
            float v = w00 * lds[bj]        + w01 * lds[bj + 1]
                    + w10 * lds[bj + 1024] + w11 * lds[bj + 1025];
            u[j] = f2bf(v);
        }
        uint2 pk;
        pk.x = (unsigned)u[0] | ((unsigned)u[1] << 16);
        pk.y = (unsigned)u[2] | ((unsigned)u[3] << 16);
        *(uint2*)(f12 + (size_t)point * C_ + cb + g * 4) = pk;
    }
}

// ---------------------------------------------------------------------------
// Kernel 2: bf16 MFMA sign-dot + masked distance stats (unchanged from R3).
// ---------------------------------------------------------------------------
__global__ __launch_bounds__(256) void k_simdist(const unsigned short* __restrict__ f12,
                                                 const float* __restrict__ ps1,
                                                 const float* __restrict__ ps2,
                                                 float* __restrict__ pmin,
                                                 float* __restrict__ psum,
                                                 float* __restrict__ pcnt) {
    int wid  = blockIdx.x * 4 + (threadIdx.x >> 6);   // 0..2047
    int lane = threadIdx.x & 63;
    int ng = wid & 15;
    int pt = (wid >> 4) & 7;
    int o  = wid >> 7;
    int quad = lane >> 4, col = lane & 15;

    const short* f12s = (const short*)f12;
    const short8* aptr =
        (const short8*)(f12s + ((size_t)(o * NP + pt * 16 + col) * C_ + quad * 8));
    short8 a[8];
    #pragma unroll
    for (int kb = 0; kb < 8; ++kb) a[kb] = aptr[kb * 4];

    const float2* ps1v = (const float2*)ps1;
    const float2* ps2v = (const float2*)ps2;
    float pxr[4], pyr[4];
    #pragma unroll
    for (int r = 0; r < 4; ++r) {
        float2 pc = ps1v[o * NP + pt * 16 + quad * 4 + r];
        pxr[r] = pc.x; pyr[r] = pc.y;
    }

    float mn[4] = {INFINITY, INFINITY, INFINITY, INFINITY};
    float sm[4] = {0.f, 0.f, 0.f, 0.f};
    float ct[4] = {0.f, 0.f, 0.f, 0.f};

    for (int t = 0; t < NT; ++t) {
        int nbase = ng * 128 + t * 16;
        const short8* bptr =
            (const short8*)(f12s + ((size_t)(NF1 + o * N2 + nbase + col) * C_ + quad * 8));
        f32x4 acc = {0.f, 0.f, 0.f, 0.f};
        #pragma unroll
        for (int kb = 0; kb < 8; ++kb)
            acc = __builtin_amdgcn_mfma_f32_16x16x32_bf16(a[kb], bptr[kb * 4], acc, 0, 0, 0);

        float2 nc = ps2v[o * N2 + nbase + col];
        #pragma unroll
        for (int r = 0; r < 4; ++r) {
            if (acc[r] >= 0.f) {                  // sims >= 0  <=>  dot >= 0
                float dx = pxr[r] - nc.x, dy = pyr[r] - nc.y;
                float d  = sqrtf(dx * dx + dy * dy);
                mn[r] = fminf(mn[r], d); sm[r] += d; ct[r] += 1.f;
            }
        }
    }

    #pragma unroll
    for (int r = 0; r < 4; ++r) {
        #pragma unroll
        for (int off = 1; off < 16; off <<= 1) {
            mn[r] = fminf(mn[r], __shfl_xor(mn[r], off, 16));
            sm[r] += __shfl_xor(sm[r], off, 16);
            ct[r] += __shfl_xor(ct[r], off, 16);
        }
    }
    if (col == 0) {
        #pragma unroll
        for (int r = 0; r < 4; ++r) {
            int p   = pt * 16 + quad * 4 + r;
            int idx = (o * NP + p) * NG + ng;     // [o][p][g]
            pmin[idx] = mn[r]; psum[idx] = sm[r]; pcnt[idx] = ct[r];
        }
    }
}

// ---------------------------------------------------------------------------
// Kernel 3: combine group partials -> scalar loss.
// ---------------------------------------------------------------------------
__global__ __launch_bounds__(1024) void k_final(const float* __restrict__ pmin,
                                                const float* __restrict__ psum,
                                                const float* __restrict__ pcnt,
                                                float* __restrict__ out) {
    int t = threadIdx.x;
    float tot = 0.f;
    for (int pair = t; pair < NOBJ * NP; pair += 1024) {
        int base = pair * NG;
        const float4* pm = (const float4*)(pmin + base);
        const float4* ps = (const float4*)(psum + base);
        const float4* pc = (const float4*)(pcnt + base);
        float mn = INFINITY, sm = 0.f, ct = 0.f;
        #pragma unroll
        for (int g4 = 0; g4 < 4; ++g4) {
            float4 a = pm[g4], bq = ps[g4], c = pc[g4];
            mn = fminf(mn, fminf(fminf(a.x, a.y), fminf(a.z, a.w)));
            sm += bq.x + bq.y + bq.z + bq.w;
            ct += c.x + c.y + c.z + c.w;
        }
        if (ct > 0.f) tot += 0.5f * (mn + sm / ct);
    }
    #pragma unroll
    for (int off = 32; off; off >>= 1) tot += __shfl_xor(tot, off, 64);
    __shared__ float wsum[16];
    if ((t & 63) == 0) wsum[t >> 6] = tot;
    __syncthreads();
    if (t < 64) {
        float v = (t < 16) ? wsum[t] : 0.f;
        #pragma unroll
        for (int off = 8; off; off >>= 1) v += __shfl_xor(v, off, 16);
        if (t == 0) out[0] = v * (1.0f / (NOBJ * NP));
    }
}

// ---------------------------------------------------------------------------
extern "C" void kernel_launch(void* const* d_in, const int* in_sizes, int n_in,
                              void* d_out, int out_size, void* d_ws, size_t ws_size,
                              hipStream_t stream) {
    const float* ps1   = (const float*)d_in[0];  // [16,128,2]
    const float* ps2   = (const float*)d_in[1];  // [16,2048,2]
    const float* feats = (const float*)d_in[2];  // [1,256,384,384]
    const float* kpts  = (const float*)d_in[3];  // [2048,2]
    float* out = (float*)d_out;

    const size_t sz_f12  = (size_t)NPTS * C_ * sizeof(unsigned short);  // 17,825,792
    const size_t sz_part = (size_t)NOBJ * NP * NG * sizeof(float);      //    131,072
    const size_t sz_cnt  = (size_t)NTILE * sizeof(int);                 //      1,344
    const size_t sz_cnt_pad = 4096;
    // list: NTILE*CAP*16 B = 1,376,256

    char* ws = (char*)d_ws;
    unsigned short* f12 = (unsigned short*)ws;
    float*  pmin = (float*) (ws + sz_f12);
    float*  psum = (float*) (ws + sz_f12 + sz_part);
    float*  pcnt = (float*) (ws + sz_f12 + 2 * sz_part);
    int*    cnts = (int*)   (ws + sz_f12 + 3 * sz_part);
    float4* list = (float4*)(ws + sz_f12 + 3 * sz_part + sz_cnt_pad);

    hipMemsetAsync(cnts, 0, sz_cnt, stream);    // ws is poisoned 0xAA each call
    k_bin<<<NPTS / 256, 256, 0, stream>>>(kpts, ps2, cnts, list);
    k_gather<<<NTILE * 16, 256, 0, stream>>>(feats, cnts, list, f12);
    k_simdist<<<NOBJ * 8 * NG / 4, 256, 0, stream>>>(f12, ps1, ps2, pmin, psum, pcnt);
    k_final<<<1, 1024, 0, stream>>>(pmin, psum, pcnt, out);
}

// Round 8
// 275.590 us; speedup vs baseline: 1.5930x; 1.0033x over previous
//
#include <hip/hip_runtime.h>
#include <hip/hip_bf16.h>
#include <math.h>

#define W_    384
#define H_    384
#define HW_   (384*384)
#define C_    256
#define NOBJ  16
#define NP    128
#define N2    2048
#define NF1   (NOBJ*NP)            // 2048 key points
#define NPTS  (NOBJ*NP + NOBJ*N2)  // 34816 total sampled points
#define NG    16                   // n-groups of 128 in simdist
#define NT    8                    // 16-wide n-tiles per group

#define TX    63                   // spatial tile width  (halo = 64 cols)
#define TY    8                    // spatial tile height (halo = 9 rows)
#define NTX   7                    // ceil(384/63); last tile 6 px wide
#define NTY   48
#define NTILE (NTX*NTY)            // 336
#define CAP   256                  // max pts/tile (mean ~104)
#define CCH   16                   // channels per gather block (16 blocks/tile)

typedef __attribute__((ext_vector_type(8))) short short8;
typedef __attribute__((ext_vector_type(4))) float f32x4;

__device__ __forceinline__ unsigned short f2bf(float v) {
    unsigned int u = __float_as_uint(v);
    u += 0x7fffu + ((u >> 16) & 1u);            // RNE f32->bf16
    return (unsigned short)(u >> 16);
}

// Async global->LDS DMA, 16 B per lane. LDS dest is wave-uniform base +
// lane*16 (m104/m108) — the layout below is constructed to match exactly.
__device__ __forceinline__ void async_g2l(const float* g, float* l) {
    __builtin_amdgcn_global_load_lds(
        (const __attribute__((address_space(1))) unsigned int*)g,
        (__attribute__((address_space(3))) unsigned int*)l, 16, 0, 0);
}

// Clamped patch base + zero-pad-folded bilinear weights (exact: OOB taps have
// zero weight). Must be identical between k_bin and k_gather.
__device__ __forceinline__ void patch_setup(float px, float py,
                                            int& ixb, int& iyb,
                                            float& w00, float& w01,
                                            float& w10, float& w11) {
    float x = px - 0.5f, y = py - 0.5f;        // img_size==(W,H): norm cancels
    float xf = floorf(x), yf = floorf(y);
    int ix0 = (int)xf, iy0 = (int)yf;
    float fx = x - xf, fy = y - yf;
    ixb = min(max(ix0, 0), W_ - 2);
    iyb = min(max(iy0, 0), H_ - 2);
    float wA = (ix0 < 0) ? fx : ((ix0 >= W_ - 1) ? 0.f : 1.f - fx);
    float wB = (ix0 < 0) ? 0.f : ((ix0 >= W_ - 1) ? 1.f - fx : fx);
    float uA = (iy0 < 0) ? fy : ((iy0 >= H_ - 1) ? 0.f : 1.f - fy);
    float uB = (iy0 < 0) ? 0.f : ((iy0 >= H_ - 1) ? 1.f - fy : fy);
    w00 = uA * wA; w01 = uA * wB; w10 = uB * wA; w11 = uB * wB;
}

// ---------------------------------------------------------------------------
// Kernel 0: bin points by spatial tile of the clamped patch base; stage
// (x, y, idx) as float4 so the gather reads one coalesced 16 B per point.
// ---------------------------------------------------------------------------
__global__ __launch_bounds__(256) void k_bin(const float* __restrict__ kpts,
                                             const float* __restrict__ ps2,
                                             int* __restrict__ counts,
                                             float4* __restrict__ list) {
    int p = blockIdx.x * 256 + threadIdx.x;    // NPTS = 136*256 exactly
    const float* src = (p < NF1) ? (kpts + (size_t)p * 2)
                                 : (ps2 + (size_t)(p - NF1) * 2);
    float px = src[0], py = src[1];
    int ixb, iyb; float w00, w01, w10, w11;
    patch_setup(px, py, ixb, iyb, w00, w01, w10, w11);
    int tile = (iyb >> 3) * NTX + ixb / TX;    // magic-mul division
    int slot = atomicAdd(&counts[tile], 1);
    if (slot < CAP) {
        float4 e; e.x = px; e.y = py; e.z = __int_as_float(p); e.w = 0.f;
        list[tile * CAP + slot] = e;
    }
}

// ---------------------------------------------------------------------------
// Kernel 1: fused tile-staged bilinear sampler, async-DMA phase 1.
// Block = (tile, 16-ch chunk). Phase 1: 9 global_load_lds (width 16) per
// wave stage the 64x9 halo x 16 ch f32 tile [dy(9)][c(16)][dx(64)] (36 KB,
// 4 blocks/CU) — no VGPR round trip, no per-row waitcnt; the __syncthreads
// vmcnt(0) is the only drain. Wave w = c-quad; lane i covers c = w*4+(i>>4),
// dx4 = (i&15)*4 so LDS offset = base + i*16 exactly as HW requires.
// Phase 2: 16 points/wave in flight, 4 lanes/point x 4 ch, ds_read_b32 taps,
// bf16 pack, 8 B coalesced f12 write per lane.
// ---------------------------------------------------------------------------
__global__ __launch_bounds__(256, 4) void k_gather(const float* __restrict__ feats,
                                                   const int* __restrict__ counts,
                                                   const float4* __restrict__ list,
                                                   unsigned short* __restrict__ f12) {
    __shared__ float lds[9 * 16 * 64];          // 36864 B
    int b    = blockIdx.x;
    int tile = b >> 4;
    int cq   = b & 15;
    int cb   = cq * CCH;
    int ty = tile / NTX, tx = tile - ty * NTX;
    int x0 = tx * TX, y0 = ty * TY;
    int t  = threadIdx.x;
    int lane = t & 63, wave = t >> 6;

    // ---- phase 1: async-stage 64x9 halo x 16 ch as f32 ----
    {
        int c   = wave * 4 + (lane >> 4);       // this lane's channel
        int dx4 = (lane & 15) * 4;              // this lane's dx quartet
        size_t cgbase = (size_t)(cb + c) * HW_ + x0 + dx4;
        const size_t LIM = (size_t)HW_ * C_ - 4;   // edge tiles overrun rows
        float* lbase = &lds[wave * 256];        // + dy*1024 below; lane*4 is HW
        #pragma unroll
        for (int dy = 0; dy < 9; ++dy) {
            int yy = min(y0 + dy, H_ - 1);
            size_t gidx = cgbase + (size_t)yy * W_;
            gidx = gidx > LIM ? LIM : gidx;     // clamped slots never read
            async_g2l(feats + gidx, lbase + dy * 1024);
        }
    }
    __syncthreads();

    // ---- phase 2: sample binned points from the LDS tile ----
    int cnt = min(counts[tile], CAP);
    int sub = lane >> 2;                        // 16 points in flight per wave
    int g   = lane & 3;                         // channel quartet within chunk

    for (int i = wave * 16 + sub; i < cnt; i += 64) {
        float4 e = list[tile * CAP + i];
        int point = __float_as_int(e.z);
        int ixb, iyb; float w00, w01, w10, w11;
        patch_setup(e.x, e.y, ixb, iyb, w00, w01, w10, w11);
        int dxb = ixb - x0, dyb = iyb - y0;
        int base0 = dyb * 1024 + (g * 4) * 64 + dxb;

        unsigned short u[4];
        #pragma unroll
        for (int j = 0; j < 4; ++j) {
            int bj = base0 + j * 64;
            float v = w00 * lds[bj]        + w01 * lds[bj + 1]
                    + w10 * lds[bj + 1024] + w11 * lds[bj + 1025];
            u[j] = f2bf(v);
        }
        uint2 pk;
        pk.x = (unsigned)u[0] | ((unsigned)u[1] << 16);
        pk.y = (unsigned)u[2] | ((unsigned)u[3] << 16);
        *(uint2*)(f12 + (size_t)point * C_ + cb + g * 4) = pk;
    }
}

// ---------------------------------------------------------------------------
// Kernel 2: bf16 MFMA sign-dot + masked distance stats (unchanged from R3).
// ---------------------------------------------------------------------------
__global__ __launch_bounds__(256) void k_simdist(const unsigned short* __restrict__ f12,
                                                 const float* __restrict__ ps1,
                                                 const float* __restrict__ ps2,
                                                 float* __restrict__ pmin,
                                                 float* __restrict__ psum,
                                                 float* __restrict__ pcnt) {
    int wid  = blockIdx.x * 4 + (threadIdx.x >> 6);   // 0..2047
    int lane = threadIdx.x & 63;
    int ng = wid & 15;
    int pt = (wid >> 4) & 7;
    int o  = wid >> 7;
    int quad = lane >> 4, col = lane & 15;

    const short* f12s = (const short*)f12;
    const short8* aptr =
        (const short8*)(f12s + ((size_t)(o * NP + pt * 16 + col) * C_ + quad * 8));
    short8 a[8];
    #pragma unroll
    for (int kb = 0; kb < 8; ++kb) a[kb] = aptr[kb * 4];

    const float2* ps1v = (const float2*)ps1;
    const float2* ps2v = (const float2*)ps2;
    float pxr[4], pyr[4];
    #pragma unroll
    for (int r = 0; r < 4; ++r) {
        float2 pc = ps1v[o * NP + pt * 16 + quad * 4 + r];
        pxr[r] = pc.x; pyr[r] = pc.y;
    }

    float mn[4] = {INFINITY, INFINITY, INFINITY, INFINITY};
    float sm[4] = {0.f, 0.f, 0.f, 0.f};
    float ct[4] = {0.f, 0.f, 0.f, 0.f};

    for (int t = 0; t < NT; ++t) {
        int nbase = ng * 128 + t * 16;
        const short8* bptr =
            (const short8*)(f12s + ((size_t)(NF1 + o * N2 + nbase + col) * C_ + quad * 8));
        f32x4 acc = {0.f, 0.f, 0.f, 0.f};
        #pragma unroll
        for (int kb = 0; kb < 8; ++kb)
            acc = __builtin_amdgcn_mfma_f32_16x16x32_bf16(a[kb], bptr[kb * 4], acc, 0, 0, 0);

        float2 nc = ps2v[o * N2 + nbase + col];
        #pragma unroll
        for (int r = 0; r < 4; ++r) {
            if (acc[r] >= 0.f) {                  // sims >= 0  <=>  dot >= 0
                float dx = pxr[r] - nc.x, dy = pyr[r] - nc.y;
                float d  = sqrtf(dx * dx + dy * dy);
                mn[r] = fminf(mn[r], d); sm[r] += d; ct[r] += 1.f;
            }
        }
    }

    #pragma unroll
    for (int r = 0; r < 4; ++r) {
        #pragma unroll
        for (int off = 1; off < 16; off <<= 1) {
            mn[r] = fminf(mn[r], __shfl_xor(mn[r], off, 16));
            sm[r] += __shfl_xor(sm[r], off, 16);
            ct[r] += __shfl_xor(ct[r], off, 16);
        }
    }
    if (col == 0) {
        #pragma unroll
        for (int r = 0; r < 4; ++r) {
            int p   = pt * 16 + quad * 4 + r;
            int idx = (o * NP + p) * NG + ng;     // [o][p][g]
            pmin[idx] = mn[r]; psum[idx] = sm[r]; pcnt[idx] = ct[r];
        }
    }
}

// ---------------------------------------------------------------------------
// Kernel 3: combine group partials -> scalar loss.
// ---------------------------------------------------------------------------
__global__ __launch_bounds__(1024) void k_final(const float* __restrict__ pmin,
                                                const float* __restrict__ psum,
                                                const float* __restrict__ pcnt,
                                                float* __restrict__ out) {
    int t = threadIdx.x;
    float tot = 0.f;
    for (int pair = t; pair < NOBJ * NP; pair += 1024) {
        int base = pair * NG;
        const float4* pm = (const float4*)(pmin + base);
        const float4* ps = (const float4*)(psum + base);
        const float4* pc = (const float4*)(pcnt + base);
        float mn = INFINITY, sm = 0.f, ct = 0.f;
        #pragma unroll
        for (int g4 = 0; g4 < 4; ++g4) {
            float4 a = pm[g4], bq = ps[g4], c = pc[g4];
            mn = fminf(mn, fminf(fminf(a.x, a.y), fminf(a.z, a.w)));
            sm += bq.x + bq.y + bq.z + bq.w;
            ct += c.x + c.y + c.z + c.w;
        }
        if (ct > 0.f) tot += 0.5f * (mn + sm / ct);
    }
    #pragma unroll
    for (int off = 32; off; off >>= 1) tot += __shfl_xor(tot, off, 64);
    __shared__ float wsum[16];
    if ((t & 63) == 0) wsum[t >> 6] = tot;
    __syncthreads();
    if (t < 64) {
        float v = (t < 16) ? wsum[t] : 0.f;
        #pragma unroll
        for (int off = 8; off; off >>= 1) v += __shfl_xor(v, off, 16);
        if (t == 0) out[0] = v * (1.0f / (NOBJ * NP));
    }
}

// ---------------------------------------------------------------------------
extern "C" void kernel_launch(void* const* d_in, const int* in_sizes, int n_in,
                              void* d_out, int out_size, void* d_ws, size_t ws_size,
                              hipStream_t stream) {
    const float* ps1   = (const float*)d_in[0];  // [16,128,2]
    const float* ps2   = (const float*)d_in[1];  // [16,2048,2]
    const float* feats = (const float*)d_in[2];  // [1,256,384,384]
    const float* kpts  = (const float*)d_in[3];  // [2048,2]
    float* out = (float*)d_out;

    const size_t sz_f12  = (size_t)NPTS * C_ * sizeof(unsigned short);  // 17,825,792
    const size_t sz_part = (size_t)NOBJ * NP * NG * sizeof(float);      //    131,072
    const size_t sz_cnt  = (size_t)NTILE * sizeof(int);                 //      1,344
    const size_t sz_cnt_pad = 4096;
    // list: NTILE*CAP*16 B = 1,376,256

    char* ws = (char*)d_ws;
    unsigned short* f12 = (unsigned short*)ws;
    float*  pmin = (float*) (ws + sz_f12);
    float*  psum = (float*) (ws + sz_f12 + sz_part);
    float*  pcnt = (float*) (ws + sz_f12 + 2 * sz_part);
    int*    cnts = (int*)   (ws + sz_f12 + 3 * sz_part);
    float4* list = (float4*)(ws + sz_f12 + 3 * sz_part + sz_cnt_pad);

    hipMemsetAsync(cnts, 0, sz_cnt, stream);    // ws is poisoned 0xAA each call
    k_bin<<<NPTS / 256, 256, 0, stream>>>(kpts, ps2, cnts, list);
    k_gather<<<NTILE * 16, 256, 0, stream>>>(feats, cnts, list, f12);
    k_simdist<<<NOBJ * 8 * NG / 4, 256, 0, stream>>>(f12, ps1, ps2, pmin, psum, pcnt);
    k_final<<<1, 1024, 0, stream>>>(pmin, psum, pcnt, out);
}